// Round 12
// baseline (167.388 us; speedup 1.0000x reference)
//
#include <hip/hip_runtime.h>
#include <hip/hip_bf16.h>

// GraphSAGE 3-layer forward on MI355X.
//  7 dispatches: memset(cnt), fill+pack (single edge pass), L1(fused agg+gemm),
//                agg128, mfma, agg128, mfma
//  Bucket CSR: edge_src[node*64 + p], p=atomicAdd (deg Poisson(12), P(>64)~1e-30).
//  Lessons: r6 — don't fuse gather into MFMA (needs occupancy).
//           r8 — grid.sync() ~75us at 600-block scale; no coop launch here.
//           r9 — edge passes are atomic-bound (int4 neutral).
//           r10 — agg128 is bandwidth-bound, not latency-bound -> r12: no
//                 weight-0 clamped duplicate loads (they waste ~25% gather BW).

#define EMB 128
#define CAP 64   // max edges per node in the bucket table

typedef __attribute__((ext_vector_type(8))) short short8v;   // 8 bf16 = 4 VGPRs
typedef __attribute__((ext_vector_type(4))) float f32x4;

static __device__ __forceinline__ float bfbits2f(unsigned short u) {
    unsigned int x = ((unsigned int)u) << 16;
    return __builtin_bit_cast(float, x);
}
static __device__ __forceinline__ unsigned short f2bfbits(float f) {
    __hip_bfloat16 h = __float2bfloat16(f);  // RTN
    return __builtin_bit_cast(unsigned short, h);
}

// ---------------- weight pack helper ----------------
// Wp[s][ct][lane][i] = W[s*32+(l>>4)*8+i][ct*16+(l&15)], W=[Wl;Wr] (256x128)
static __device__ __forceinline__ void pack_one(int t, const float* __restrict__ Wl,
                                                const float* __restrict__ Wr,
                                                unsigned short* __restrict__ Wp) {
    const int s = t >> 9;
    const int ct = (t >> 6) & 7;
    const int l = t & 63;
    const int k0 = s * 32 + (l >> 4) * 8;
    const int c = ct * 16 + (l & 15);
    unsigned short frag[8];
#pragma unroll
    for (int i = 0; i < 8; ++i) {
        const int k = k0 + i;
        const float v = (k < 128) ? Wl[(size_t)k * EMB + c] : Wr[(size_t)(k - 128) * EMB + c];
        frag[i] = f2bfbits(v);
    }
    *(short8v*)(Wp + (size_t)t * 8) = *(const short8v*)frag;
}

// ---------------- bucket build: single edge pass + weight pack ----------------

__global__ __launch_bounds__(256) void fill_pack_kernel(const int* __restrict__ src,
                                                        const int* __restrict__ dst,
                                                        int* __restrict__ cnt,
                                                        int* __restrict__ edge_src,
                                                        int e, int cbq,
                                                        const float* __restrict__ W2l,
                                                        const float* __restrict__ W2r,
                                                        const float* __restrict__ W3l,
                                                        const float* __restrict__ W3r,
                                                        unsigned short* __restrict__ Wp2,
                                                        unsigned short* __restrict__ Wp3) {
    if ((int)blockIdx.x < cbq) {
        const int i4 = (blockIdx.x * 256 + threadIdx.x) * 4;
        if (i4 + 3 < e) {
            const int4 d4 = *(const int4*)(dst + i4);
            const int4 s4 = *(const int4*)(src + i4);
            edge_src[(size_t)d4.x * CAP + atomicAdd(&cnt[d4.x], 1)] = s4.x;
            edge_src[(size_t)d4.y * CAP + atomicAdd(&cnt[d4.y], 1)] = s4.y;
            edge_src[(size_t)d4.z * CAP + atomicAdd(&cnt[d4.z], 1)] = s4.z;
            edge_src[(size_t)d4.w * CAP + atomicAdd(&cnt[d4.w], 1)] = s4.w;
        } else {
            for (int i = i4; i < e; ++i) {
                const int d = dst[i];
                edge_src[(size_t)d * CAP + atomicAdd(&cnt[d], 1)] = src[i];
            }
        }
        return;
    }
    int pt = ((int)blockIdx.x - cbq) * 256 + threadIdx.x;  // 0..8191
    if (pt < 4096) pack_one(pt, W2l, W2r, Wp2);
    else           pack_one(pt - 4096, W3l, W3r, Wp3);
}

// ---------------- layer 1 fused: agg8 + fp32 GEMM (K=8) -> bf16 h1 ----------------

__global__ __launch_bounds__(256) void fused_l1_kernel(const float* __restrict__ x,
                                                       const int* __restrict__ cnt,
                                                       const int* __restrict__ edge_src,
                                                       const float* __restrict__ W1l,
                                                       const float* __restrict__ W1r,
                                                       const float* __restrict__ bias,
                                                       unsigned short* __restrict__ outb,
                                                       int n) {
    __shared__ float As[32][8];
    __shared__ float Bs[32][8];
    const int t = threadIdx.x;
    const int rb = blockIdx.x * 32;

    {   // phase 1: aggregation (node = rb + t>>3, channel = t&7); exact loads
        const int node8 = t >> 3;
        const int ch = t & 7;
        const int node = rb + node8;
        float a = 0.f, b = 0.f, bsv = 0.f, di = 0.f;
        if (node < n) {
            const int c_n = cnt[node];
            const int base = node * CAP;
            int e = 0;
            for (; e + 4 <= c_n; e += 4) {
                const int sa = edge_src[base + e];
                const int sb = edge_src[base + e + 1];
                const int sc = edge_src[base + e + 2];
                const int sd = edge_src[base + e + 3];
                a += x[(size_t)sa * 8 + ch];
                b += x[(size_t)sb * 8 + ch];
                a += x[(size_t)sc * 8 + ch];
                b += x[(size_t)sd * 8 + ch];
            }
            for (; e < c_n; ++e) a += x[(size_t)edge_src[base + e] * 8 + ch];
            di = (c_n > 0) ? 1.0f / (float)c_n : 0.f;
            bsv = x[(size_t)node * 8 + ch];
        }
        As[node8][ch] = (a + b) * di;
        Bs[node8][ch] = bsv;
    }
    __syncthreads();

    const int tx = t & 31;
    const int ty = t >> 5;
    const int c0 = tx * 4;

    const float4 bv = *(const float4*)(bias + c0);
    float4 acc[4] = {bv, bv, bv, bv};

#pragma unroll
    for (int k = 0; k < 8; k += 4) {
        float4 a4[4], b4[4];
#pragma unroll
        for (int i = 0; i < 4; ++i) {
            a4[i] = *(const float4*)&As[ty + 8 * i][k];
            b4[i] = *(const float4*)&Bs[ty + 8 * i][k];
        }
#pragma unroll
        for (int kk = 0; kk < 4; ++kk) {
            const float4 wl = *(const float4*)(W1l + (size_t)(k + kk) * EMB + c0);
            const float4 wr = *(const float4*)(W1r + (size_t)(k + kk) * EMB + c0);
#pragma unroll
            for (int i = 0; i < 4; ++i) {
                const float av = ((const float*)&a4[i])[kk];
                const float bw = ((const float*)&b4[i])[kk];
                acc[i].x = fmaf(av, wl.x, acc[i].x);
                acc[i].y = fmaf(av, wl.y, acc[i].y);
                acc[i].z = fmaf(av, wl.z, acc[i].z);
                acc[i].w = fmaf(av, wl.w, acc[i].w);
                acc[i].x = fmaf(bw, wr.x, acc[i].x);
                acc[i].y = fmaf(bw, wr.y, acc[i].y);
                acc[i].z = fmaf(bw, wr.z, acc[i].z);
                acc[i].w = fmaf(bw, wr.w, acc[i].w);
            }
        }
    }

#pragma unroll
    for (int i = 0; i < 4; ++i) {
        int r = rb + ty + 8 * i;
        if (r < n) {
            float4 v = acc[i];
            v.x = fmaxf(v.x, 0.f); v.y = fmaxf(v.y, 0.f);
            v.z = fmaxf(v.z, 0.f); v.w = fmaxf(v.w, 0.f);
            unsigned long long pk = (unsigned long long)f2bfbits(v.x) |
                                    ((unsigned long long)f2bfbits(v.y) << 16) |
                                    ((unsigned long long)f2bfbits(v.z) << 32) |
                                    ((unsigned long long)f2bfbits(v.w) << 48);
            *(unsigned long long*)(outb + (size_t)r * EMB + c0) = pk;
        }
    }
}

// ---------------- aggregation (d=128, bf16) ----------------
// One wave per node; 16 lanes per edge-row (uint4 = 8 channels = 16B/lane,
// 256B/edge contiguous); 4 lane-groups process interleaved edges (e += 4),
// EXACT loads only (no weight-0 duplicates — gather is bandwidth-bound, r10).
// Cross-group combine: shfl_xor 16, 32 (cl = l&15 invariant).

__global__ __launch_bounds__(256) void agg128_bf16_kernel(const unsigned short* __restrict__ hb,
                                                          const int* __restrict__ cnt,
                                                          const int* __restrict__ edge_src,
                                                          unsigned short* __restrict__ aggb,
                                                          int n) {
    const int wave = threadIdx.x >> 6;
    const int lane = threadIdx.x & 63;
    const int grp = lane >> 4;    // lane-group = edge slot (mod 4)
    const int cl = lane & 15;     // channel group: channels 8*cl..8*cl+7
    const int node = blockIdx.x * 4 + wave;
    if (node >= n) return;
    const int c_n = cnt[node];
    const int base = node * CAP;
    const size_t coff = (size_t)cl * 8;
    float a[8] = {};
    for (int e = grp; e < c_n; e += 4) {
        const int sa = edge_src[base + e];
        const uint4 va = *(const uint4*)(hb + (size_t)sa * EMB + coff);
        a[0] += bfbits2f((unsigned short)va.x);
        a[1] += bfbits2f((unsigned short)(va.x >> 16));
        a[2] += bfbits2f((unsigned short)va.y);
        a[3] += bfbits2f((unsigned short)(va.y >> 16));
        a[4] += bfbits2f((unsigned short)va.z);
        a[5] += bfbits2f((unsigned short)(va.z >> 16));
        a[6] += bfbits2f((unsigned short)va.w);
        a[7] += bfbits2f((unsigned short)(va.w >> 16));
    }
#pragma unroll
    for (int i = 0; i < 8; ++i) {
        a[i] += __shfl_xor(a[i], 16);
        a[i] += __shfl_xor(a[i], 32);
    }
    if (grp == 0) {
        const float di = (c_n > 0) ? 1.0f / (float)c_n : 0.f;
        uint4 o;
        o.x = (unsigned int)f2bfbits(a[0] * di) | ((unsigned int)f2bfbits(a[1] * di) << 16);
        o.y = (unsigned int)f2bfbits(a[2] * di) | ((unsigned int)f2bfbits(a[3] * di) << 16);
        o.z = (unsigned int)f2bfbits(a[4] * di) | ((unsigned int)f2bfbits(a[5] * di) << 16);
        o.w = (unsigned int)f2bfbits(a[6] * di) | ((unsigned int)f2bfbits(a[7] * di) << 16);
        *(uint4*)(aggb + (size_t)node * EMB + coff) = o;
    }
}

// ---------------- MFMA GEMM: out = act([Ab|Hb] @ Wp + bias + skip) ----------------
// 256 threads = 4 waves; block tile 64 rows; K=256 in 8 steps of 32.
// C/D layout [m89]: col = ct*16 + (l&15), row = rowbase + (l>>4)*4 + reg.
// FINAL (non-re-read) output store is non-temporal to protect L2 for gathers.

template <bool RELU, bool WRITEB, bool SKIPB, bool NTOUT>
__global__ __launch_bounds__(256) void mfma_gemm_kernel(const unsigned short* __restrict__ Ab,
                                                        const unsigned short* __restrict__ Hb,
                                                        const unsigned short* __restrict__ Wp,
                                                        const float* __restrict__ bias,
                                                        const float* skipf,
                                                        const unsigned short* skipb,
                                                        float* outf,
                                                        unsigned short* __restrict__ outb,
                                                        int n) {
    const int l = threadIdx.x & 63;
    const int w = threadIdx.x >> 6;
    const int rowbase = blockIdx.x * 64 + w * 16;
    const int lr = l & 15;
    const int lg = l >> 4;

    int r0 = rowbase + lr;
    if (r0 > n - 1) r0 = n - 1;  // clamp: loads in-bounds, results discarded
    const size_t arow = (size_t)r0 * EMB + lg * 8;

    f32x4 acc[8] = {};

#pragma unroll
    for (int s = 0; s < 8; ++s) {
        const unsigned short* abase = (s < 4) ? (Ab + arow + s * 32)
                                              : (Hb + arow + (s - 4) * 32);
        const short8v af = *(const short8v*)abase;
        const unsigned short* wbase = Wp + ((size_t)(s * 8) * 64 + l) * 8;
#pragma unroll
        for (int ct = 0; ct < 8; ++ct) {
            const short8v bfr = *(const short8v*)(wbase + (size_t)ct * 64 * 8);
            acc[ct] = __builtin_amdgcn_mfma_f32_16x16x32_bf16(af, bfr, acc[ct], 0, 0, 0);
        }
    }

#pragma unroll
    for (int ct = 0; ct < 8; ++ct) {
        const int c = ct * 16 + lr;
        const float bv = bias[c];
#pragma unroll
        for (int j = 0; j < 4; ++j) {
            const int r = rowbase + lg * 4 + j;
            if (r < n) {
                const float sk = SKIPB ? bfbits2f(skipb[(size_t)r * EMB + c])
                                       : skipf[(size_t)r * EMB + c];
                float v = acc[ct][j] + bv + sk;
                if (RELU) v = fmaxf(v, 0.f);
                if (NTOUT) __builtin_nontemporal_store(v, outf + (size_t)r * EMB + c);
                else       outf[(size_t)r * EMB + c] = v;
                if (WRITEB) outb[(size_t)r * EMB + c] = f2bfbits(v);
            }
        }
    }
}

// ---------------- launcher ----------------

extern "C" void kernel_launch(void* const* d_in, const int* in_sizes, int n_in,
                              void* d_out, int out_size, void* d_ws, size_t ws_size,
                              hipStream_t stream) {
    const float* x   = (const float*)d_in[0];
    const int*   src = (const int*)d_in[1];
    const int*   dst = (const int*)d_in[2];
    const float* W1l = (const float*)d_in[3];
    const float* W1r = (const float*)d_in[4];
    const float* b1  = (const float*)d_in[5];
    const float* W2l = (const float*)d_in[6];
    const float* W2r = (const float*)d_in[7];
    const float* b2  = (const float*)d_in[8];
    const float* W3l = (const float*)d_in[9];
    const float* W3r = (const float*)d_in[10];
    const float* b3  = (const float*)d_in[11];
    float* out = (float*)d_out;

    const int N = in_sizes[0] / 8;
    const int E = in_sizes[1];

    // workspace layout (~78 MB)
    char* ws = (char*)d_ws;
    const size_t hbytes  = (size_t)N * EMB * sizeof(float);           // 25.6 MB
    const size_t hbbytes = (size_t)N * EMB * sizeof(unsigned short);  // 12.8 MB
    float* h2f = (float*)ws;
    unsigned short* h1b  = (unsigned short*)(ws + hbytes);
    unsigned short* h2b  = (unsigned short*)(ws + hbytes + hbbytes);
    unsigned short* aggb = (unsigned short*)(ws + hbytes + 2 * hbbytes);
    char* p = ws + hbytes + 3 * hbbytes;
    unsigned short* Wp2 = (unsigned short*)p;  p += 4096 * 8 * sizeof(unsigned short);
    unsigned short* Wp3 = (unsigned short*)p;  p += 4096 * 8 * sizeof(unsigned short);
    int* cnt      = (int*)p;                   p += (size_t)N * sizeof(int);
    int* edge_src = (int*)p;                   // N * CAP ints = 12.8 MB

    const int cbq = ((E + 3) / 4 + 255) / 256;  // int4 edge blocks (586)

    // bucket build: zero cnt, then single scatter pass (+ weight pack)
    hipMemsetAsync(cnt, 0, (size_t)N * sizeof(int), stream);
    fill_pack_kernel<<<cbq + 32, 256, 0, stream>>>(src, dst, cnt, edge_src, E, cbq,
                                                   W2l, W2r, W3l, W3r, Wp2, Wp3);

    const int agg_grid  = (N + 3) / 4;
    const int mfma_grid = (N + 63) / 64;

    // layer 1: h1 = relu(agg8(x)@W1l + x@W1r + b1)  [fused agg+GEMM; bf16 h1]
    fused_l1_kernel<<<(N + 31) / 32, 256, 0, stream>>>(
        x, cnt, edge_src, W1l, W1r, b1, h1b, N);

    // layer 2: h2 = relu([agg(h1)|h1]@[W2l;W2r] + b2 + h1)   [skip from bf16 h1]
    agg128_bf16_kernel<<<agg_grid, 256, 0, stream>>>(h1b, cnt, edge_src, aggb, N);
    mfma_gemm_kernel<true, true, true, false><<<mfma_grid, 256, 0, stream>>>(
        aggb, h1b, Wp2, b2, nullptr, h1b, h2f, h2b, N);

    // layer 3: out = [agg(h2)|h2]@[W3l;W3r] + b3 + h2        [skip from fp32 h2]
    agg128_bf16_kernel<<<agg_grid, 256, 0, stream>>>(h2b, cnt, edge_src, aggb, N);
    mfma_gemm_kernel<false, false, false, true><<<mfma_grid, 256, 0, stream>>>(
        aggb, h2b, Wp3, b3, h2f, nullptr, out, nullptr, N);
}

// Round 13
// 152.709 us; speedup vs baseline: 1.0961x; 1.0961x over previous
//
#include <hip/hip_runtime.h>
#include <hip/hip_bf16.h>

// GraphSAGE 3-layer forward on MI355X.
//  7 dispatches: memset(cnt), fill+pack (single edge pass), L1(fused agg+gemm),
//                agg128, mfma, agg128, mfma
//  Bucket CSR: edge_src[node*64 + p], p=atomicAdd (deg Poisson(12), P(>64)~1e-30).
//  Lessons: r6 — don't fuse gather into MFMA (needs occupancy).
//           r8 — grid.sync() ~75us at 600-block scale; no coop launch here.
//           r9 — edge passes are atomic-bound (int4 neutral).
//           r12 — clamped duplicate gather loads are cache-hot (~free); cutting
//                 in-flight loads 8->4 cost +12us. Keep >=8 in flight; r13: 16.

#define EMB 128
#define CAP 64   // max edges per node in the bucket table

typedef __attribute__((ext_vector_type(8))) short short8v;   // 8 bf16 = 4 VGPRs
typedef __attribute__((ext_vector_type(4))) float f32x4;

static __device__ __forceinline__ float bfbits2f(unsigned short u) {
    unsigned int x = ((unsigned int)u) << 16;
    return __builtin_bit_cast(float, x);
}
static __device__ __forceinline__ unsigned short f2bfbits(float f) {
    __hip_bfloat16 h = __float2bfloat16(f);  // RTN
    return __builtin_bit_cast(unsigned short, h);
}

// ---------------- weight pack helper ----------------
// Wp[s][ct][lane][i] = W[s*32+(l>>4)*8+i][ct*16+(l&15)], W=[Wl;Wr] (256x128)
static __device__ __forceinline__ void pack_one(int t, const float* __restrict__ Wl,
                                                const float* __restrict__ Wr,
                                                unsigned short* __restrict__ Wp) {
    const int s = t >> 9;
    const int ct = (t >> 6) & 7;
    const int l = t & 63;
    const int k0 = s * 32 + (l >> 4) * 8;
    const int c = ct * 16 + (l & 15);
    unsigned short frag[8];
#pragma unroll
    for (int i = 0; i < 8; ++i) {
        const int k = k0 + i;
        const float v = (k < 128) ? Wl[(size_t)k * EMB + c] : Wr[(size_t)(k - 128) * EMB + c];
        frag[i] = f2bfbits(v);
    }
    *(short8v*)(Wp + (size_t)t * 8) = *(const short8v*)frag;
}

// ---------------- bucket build: single edge pass + weight pack ----------------

__global__ __launch_bounds__(256) void fill_pack_kernel(const int* __restrict__ src,
                                                        const int* __restrict__ dst,
                                                        int* __restrict__ cnt,
                                                        int* __restrict__ edge_src,
                                                        int e, int cbq,
                                                        const float* __restrict__ W2l,
                                                        const float* __restrict__ W2r,
                                                        const float* __restrict__ W3l,
                                                        const float* __restrict__ W3r,
                                                        unsigned short* __restrict__ Wp2,
                                                        unsigned short* __restrict__ Wp3) {
    if ((int)blockIdx.x < cbq) {
        const int i4 = (blockIdx.x * 256 + threadIdx.x) * 4;
        if (i4 + 3 < e) {
            const int4 d4 = *(const int4*)(dst + i4);
            const int4 s4 = *(const int4*)(src + i4);
            edge_src[(size_t)d4.x * CAP + atomicAdd(&cnt[d4.x], 1)] = s4.x;
            edge_src[(size_t)d4.y * CAP + atomicAdd(&cnt[d4.y], 1)] = s4.y;
            edge_src[(size_t)d4.z * CAP + atomicAdd(&cnt[d4.z], 1)] = s4.z;
            edge_src[(size_t)d4.w * CAP + atomicAdd(&cnt[d4.w], 1)] = s4.w;
        } else {
            for (int i = i4; i < e; ++i) {
                const int d = dst[i];
                edge_src[(size_t)d * CAP + atomicAdd(&cnt[d], 1)] = src[i];
            }
        }
        return;
    }
    int pt = ((int)blockIdx.x - cbq) * 256 + threadIdx.x;  // 0..8191
    if (pt < 4096) pack_one(pt, W2l, W2r, Wp2);
    else           pack_one(pt - 4096, W3l, W3r, Wp3);
}

// ---------------- layer 1 fused: agg8 + fp32 GEMM (K=8) -> bf16 h1 ----------------
// (r11 form: clamped weight-0 quad loads keep 4 in flight incl. tail)

__global__ __launch_bounds__(256) void fused_l1_kernel(const float* __restrict__ x,
                                                       const int* __restrict__ cnt,
                                                       const int* __restrict__ edge_src,
                                                       const float* __restrict__ W1l,
                                                       const float* __restrict__ W1r,
                                                       const float* __restrict__ bias,
                                                       unsigned short* __restrict__ outb,
                                                       int n) {
    __shared__ float As[32][8];
    __shared__ float Bs[32][8];
    const int t = threadIdx.x;
    const int rb = blockIdx.x * 32;

    {   // phase 1: aggregation (node = rb + t>>3, channel = t&7)
        const int node8 = t >> 3;
        const int ch = t & 7;
        const int node = rb + node8;
        float a = 0.f, bsv = 0.f, di = 0.f;
        if (node < n) {
            const int c_n = cnt[node];
            const int base = node * CAP;
            for (int e = 0; e < c_n; e += 4) {
                const int sa = edge_src[base + e];
                const int sb = edge_src[base + min(e + 1, c_n - 1)];
                const int sc = edge_src[base + min(e + 2, c_n - 1)];
                const int sd = edge_src[base + min(e + 3, c_n - 1)];
                const float f1 = (e + 1 < c_n) ? 1.f : 0.f;
                const float f2 = (e + 2 < c_n) ? 1.f : 0.f;
                const float f3 = (e + 3 < c_n) ? 1.f : 0.f;
                a += x[(size_t)sa * 8 + ch];
                a = fmaf(f1, x[(size_t)sb * 8 + ch], a);
                a = fmaf(f2, x[(size_t)sc * 8 + ch], a);
                a = fmaf(f3, x[(size_t)sd * 8 + ch], a);
            }
            di = (c_n > 0) ? 1.0f / (float)c_n : 0.f;
            bsv = x[(size_t)node * 8 + ch];
        }
        As[node8][ch] = a * di;
        Bs[node8][ch] = bsv;
    }
    __syncthreads();

    const int tx = t & 31;
    const int ty = t >> 5;
    const int c0 = tx * 4;

    const float4 bv = *(const float4*)(bias + c0);
    float4 acc[4] = {bv, bv, bv, bv};

#pragma unroll
    for (int k = 0; k < 8; k += 4) {
        float4 a4[4], b4[4];
#pragma unroll
        for (int i = 0; i < 4; ++i) {
            a4[i] = *(const float4*)&As[ty + 8 * i][k];
            b4[i] = *(const float4*)&Bs[ty + 8 * i][k];
        }
#pragma unroll
        for (int kk = 0; kk < 4; ++kk) {
            const float4 wl = *(const float4*)(W1l + (size_t)(k + kk) * EMB + c0);
            const float4 wr = *(const float4*)(W1r + (size_t)(k + kk) * EMB + c0);
#pragma unroll
            for (int i = 0; i < 4; ++i) {
                const float av = ((const float*)&a4[i])[kk];
                const float bw = ((const float*)&b4[i])[kk];
                acc[i].x = fmaf(av, wl.x, acc[i].x);
                acc[i].y = fmaf(av, wl.y, acc[i].y);
                acc[i].z = fmaf(av, wl.z, acc[i].z);
                acc[i].w = fmaf(av, wl.w, acc[i].w);
                acc[i].x = fmaf(bw, wr.x, acc[i].x);
                acc[i].y = fmaf(bw, wr.y, acc[i].y);
                acc[i].z = fmaf(bw, wr.z, acc[i].z);
                acc[i].w = fmaf(bw, wr.w, acc[i].w);
            }
        }
    }

#pragma unroll
    for (int i = 0; i < 4; ++i) {
        int r = rb + ty + 8 * i;
        if (r < n) {
            float4 v = acc[i];
            v.x = fmaxf(v.x, 0.f); v.y = fmaxf(v.y, 0.f);
            v.z = fmaxf(v.z, 0.f); v.w = fmaxf(v.w, 0.f);
            unsigned long long pk = (unsigned long long)f2bfbits(v.x) |
                                    ((unsigned long long)f2bfbits(v.y) << 16) |
                                    ((unsigned long long)f2bfbits(v.z) << 32) |
                                    ((unsigned long long)f2bfbits(v.w) << 48);
            *(unsigned long long*)(outb + (size_t)r * EMB + c0) = pk;
        }
    }
}

// ---------------- aggregation (d=128, bf16) ----------------
// One wave per node; 16 lanes per edge-row (uint4 = 8 channels = 16B/lane,
// 256B/edge contiguous); 4 lane-groups x 4 clamped loads per iteration =
// 16 edges in flight per wave (clamped duplicates are cache-hot ~free, r12).
// Cross-group combine: shfl_xor 16, 32 (cl = l&15 invariant).

__global__ __launch_bounds__(256) void agg128_bf16_kernel(const unsigned short* __restrict__ hb,
                                                          const int* __restrict__ cnt,
                                                          const int* __restrict__ edge_src,
                                                          unsigned short* __restrict__ aggb,
                                                          int n) {
    const int wave = threadIdx.x >> 6;
    const int lane = threadIdx.x & 63;
    const int grp = lane >> 4;    // lane-group = edge slot (mod 4)
    const int cl = lane & 15;     // channel group: channels 8*cl..8*cl+7
    const int node = blockIdx.x * 4 + wave;
    if (node >= n) return;
    const int c_n = cnt[node];
    const int base = node * CAP;
    const size_t coff = (size_t)cl * 8;
    float a[8] = {};
    for (int e = grp; e < c_n; e += 16) {
        const int e1 = min(e + 4, c_n - 1);
        const int e2 = min(e + 8, c_n - 1);
        const int e3 = min(e + 12, c_n - 1);
        const float f1 = (e + 4 < c_n) ? 1.f : 0.f;
        const float f2 = (e + 8 < c_n) ? 1.f : 0.f;
        const float f3 = (e + 12 < c_n) ? 1.f : 0.f;
        const int sa = edge_src[base + e];
        const int sb = edge_src[base + e1];
        const int sc = edge_src[base + e2];
        const int sd = edge_src[base + e3];
        const uint4 va = *(const uint4*)(hb + (size_t)sa * EMB + coff);
        const uint4 vb = *(const uint4*)(hb + (size_t)sb * EMB + coff);
        const uint4 vc = *(const uint4*)(hb + (size_t)sc * EMB + coff);
        const uint4 vd = *(const uint4*)(hb + (size_t)sd * EMB + coff);
        a[0] += bfbits2f((unsigned short)va.x);
        a[1] += bfbits2f((unsigned short)(va.x >> 16));
        a[2] += bfbits2f((unsigned short)va.y);
        a[3] += bfbits2f((unsigned short)(va.y >> 16));
        a[4] += bfbits2f((unsigned short)va.z);
        a[5] += bfbits2f((unsigned short)(va.z >> 16));
        a[6] += bfbits2f((unsigned short)va.w);
        a[7] += bfbits2f((unsigned short)(va.w >> 16));
        a[0] = fmaf(f1, bfbits2f((unsigned short)vb.x), a[0]);
        a[1] = fmaf(f1, bfbits2f((unsigned short)(vb.x >> 16)), a[1]);
        a[2] = fmaf(f1, bfbits2f((unsigned short)vb.y), a[2]);
        a[3] = fmaf(f1, bfbits2f((unsigned short)(vb.y >> 16)), a[3]);
        a[4] = fmaf(f1, bfbits2f((unsigned short)vb.z), a[4]);
        a[5] = fmaf(f1, bfbits2f((unsigned short)(vb.z >> 16)), a[5]);
        a[6] = fmaf(f1, bfbits2f((unsigned short)vb.w), a[6]);
        a[7] = fmaf(f1, bfbits2f((unsigned short)(vb.w >> 16)), a[7]);
        a[0] = fmaf(f2, bfbits2f((unsigned short)vc.x), a[0]);
        a[1] = fmaf(f2, bfbits2f((unsigned short)(vc.x >> 16)), a[1]);
        a[2] = fmaf(f2, bfbits2f((unsigned short)vc.y), a[2]);
        a[3] = fmaf(f2, bfbits2f((unsigned short)(vc.y >> 16)), a[3]);
        a[4] = fmaf(f2, bfbits2f((unsigned short)vc.z), a[4]);
        a[5] = fmaf(f2, bfbits2f((unsigned short)(vc.z >> 16)), a[5]);
        a[6] = fmaf(f2, bfbits2f((unsigned short)vc.w), a[6]);
        a[7] = fmaf(f2, bfbits2f((unsigned short)(vc.w >> 16)), a[7]);
        a[0] = fmaf(f3, bfbits2f((unsigned short)vd.x), a[0]);
        a[1] = fmaf(f3, bfbits2f((unsigned short)(vd.x >> 16)), a[1]);
        a[2] = fmaf(f3, bfbits2f((unsigned short)vd.y), a[2]);
        a[3] = fmaf(f3, bfbits2f((unsigned short)(vd.y >> 16)), a[3]);
        a[4] = fmaf(f3, bfbits2f((unsigned short)vd.z), a[4]);
        a[5] = fmaf(f3, bfbits2f((unsigned short)(vd.z >> 16)), a[5]);
        a[6] = fmaf(f3, bfbits2f((unsigned short)vd.w), a[6]);
        a[7] = fmaf(f3, bfbits2f((unsigned short)(vd.w >> 16)), a[7]);
    }
#pragma unroll
    for (int i = 0; i < 8; ++i) {
        a[i] += __shfl_xor(a[i], 16);
        a[i] += __shfl_xor(a[i], 32);
    }
    if (grp == 0) {
        const float di = (c_n > 0) ? 1.0f / (float)c_n : 0.f;
        uint4 o;
        o.x = (unsigned int)f2bfbits(a[0] * di) | ((unsigned int)f2bfbits(a[1] * di) << 16);
        o.y = (unsigned int)f2bfbits(a[2] * di) | ((unsigned int)f2bfbits(a[3] * di) << 16);
        o.z = (unsigned int)f2bfbits(a[4] * di) | ((unsigned int)f2bfbits(a[5] * di) << 16);
        o.w = (unsigned int)f2bfbits(a[6] * di) | ((unsigned int)f2bfbits(a[7] * di) << 16);
        *(uint4*)(aggb + (size_t)node * EMB + coff) = o;
    }
}

// ---------------- MFMA GEMM: out = act([Ab|Hb] @ Wp + bias + skip) ----------------
// 256 threads = 4 waves; block tile 64 rows; K=256 in 8 steps of 32.
// C/D layout [m89]: col = ct*16 + (l&15), row = rowbase + (l>>4)*4 + reg.

template <bool RELU, bool WRITEB, bool SKIPB>
__global__ __launch_bounds__(256) void mfma_gemm_kernel(const unsigned short* __restrict__ Ab,
                                                        const unsigned short* __restrict__ Hb,
                                                        const unsigned short* __restrict__ Wp,
                                                        const float* __restrict__ bias,
                                                        const float* skipf,
                                                        const unsigned short* skipb,
                                                        float* outf,
                                                        unsigned short* __restrict__ outb,
                                                        int n) {
    const int l = threadIdx.x & 63;
    const int w = threadIdx.x >> 6;
    const int rowbase = blockIdx.x * 64 + w * 16;
    const int lr = l & 15;
    const int lg = l >> 4;

    int r0 = rowbase + lr;
    if (r0 > n - 1) r0 = n - 1;  // clamp: loads in-bounds, results discarded
    const size_t arow = (size_t)r0 * EMB + lg * 8;

    f32x4 acc[8] = {};

#pragma unroll
    for (int s = 0; s < 8; ++s) {
        const unsigned short* abase = (s < 4) ? (Ab + arow + s * 32)
                                              : (Hb + arow + (s - 4) * 32);
        const short8v af = *(const short8v*)abase;
        const unsigned short* wbase = Wp + ((size_t)(s * 8) * 64 + l) * 8;
#pragma unroll
        for (int ct = 0; ct < 8; ++ct) {
            const short8v bfr = *(const short8v*)(wbase + (size_t)ct * 64 * 8);
            acc[ct] = __builtin_amdgcn_mfma_f32_16x16x32_bf16(af, bfr, acc[ct], 0, 0, 0);
        }
    }

#pragma unroll
    for (int ct = 0; ct < 8; ++ct) {
        const int c = ct * 16 + lr;
        const float bv = bias[c];
#pragma unroll
        for (int j = 0; j < 4; ++j) {
            const int r = rowbase + lg * 4 + j;
            if (r < n) {
                const float sk = SKIPB ? bfbits2f(skipb[(size_t)r * EMB + c])
                                       : skipf[(size_t)r * EMB + c];
                float v = acc[ct][j] + bv + sk;
                if (RELU) v = fmaxf(v, 0.f);
                outf[(size_t)r * EMB + c] = v;
                if (WRITEB) outb[(size_t)r * EMB + c] = f2bfbits(v);
            }
        }
    }
}

// ---------------- launcher ----------------

extern "C" void kernel_launch(void* const* d_in, const int* in_sizes, int n_in,
                              void* d_out, int out_size, void* d_ws, size_t ws_size,
                              hipStream_t stream) {
    const float* x   = (const float*)d_in[0];
    const int*   src = (const int*)d_in[1];
    const int*   dst = (const int*)d_in[2];
    const float* W1l = (const float*)d_in[3];
    const float* W1r = (const float*)d_in[4];
    const float* b1  = (const float*)d_in[5];
    const float* W2l = (const float*)d_in[6];
    const float* W2r = (const float*)d_in[7];
    const float* b2  = (const float*)d_in[8];
    const float* W3l = (const float*)d_in[9];
    const float* W3r = (const float*)d_in[10];
    const float* b3  = (const float*)d_in[11];
    float* out = (float*)d_out;

    const int N = in_sizes[0] / 8;
    const int E = in_sizes[1];

    // workspace layout (~78 MB)
    char* ws = (char*)d_ws;
    const size_t hbytes  = (size_t)N * EMB * sizeof(float);           // 25.6 MB
    const size_t hbbytes = (size_t)N * EMB * sizeof(unsigned short);  // 12.8 MB
    float* h2f = (float*)ws;
    unsigned short* h1b  = (unsigned short*)(ws + hbytes);
    unsigned short* h2b  = (unsigned short*)(ws + hbytes + hbbytes);
    unsigned short* aggb = (unsigned short*)(ws + hbytes + 2 * hbbytes);
    char* p = ws + hbytes + 3 * hbbytes;
    unsigned short* Wp2 = (unsigned short*)p;  p += 4096 * 8 * sizeof(unsigned short);
    unsigned short* Wp3 = (unsigned short*)p;  p += 4096 * 8 * sizeof(unsigned short);
    int* cnt      = (int*)p;                   p += (size_t)N * sizeof(int);
    int* edge_src = (int*)p;                   // N * CAP ints = 12.8 MB

    const int cbq = ((E + 3) / 4 + 255) / 256;  // int4 edge blocks (586)

    // bucket build: zero cnt, then single scatter pass (+ weight pack)
    hipMemsetAsync(cnt, 0, (size_t)N * sizeof(int), stream);
    fill_pack_kernel<<<cbq + 32, 256, 0, stream>>>(src, dst, cnt, edge_src, E, cbq,
                                                   W2l, W2r, W3l, W3r, Wp2, Wp3);

    const int agg_grid  = (N + 3) / 4;
    const int mfma_grid = (N + 63) / 64;

    // layer 1: h1 = relu(agg8(x)@W1l + x@W1r + b1)  [fused agg+GEMM; bf16 h1]
    fused_l1_kernel<<<(N + 31) / 32, 256, 0, stream>>>(
        x, cnt, edge_src, W1l, W1r, b1, h1b, N);

    // layer 2: h2 = relu([agg(h1)|h1]@[W2l;W2r] + b2 + h1)   [skip from bf16 h1]
    agg128_bf16_kernel<<<agg_grid, 256, 0, stream>>>(h1b, cnt, edge_src, aggb, N);
    mfma_gemm_kernel<true, true, true><<<mfma_grid, 256, 0, stream>>>(
        aggb, h1b, Wp2, b2, nullptr, h1b, h2f, h2b, N);

    // layer 3: out = [agg(h2)|h2]@[W3l;W3r] + b3 + h2        [skip from fp32 h2]
    agg128_bf16_kernel<<<agg_grid, 256, 0, stream>>>(h2b, cnt, edge_src, aggb, N);
    mfma_gemm_kernel<false, false, false><<<mfma_grid, 256, 0, stream>>>(
        aggb, h2b, Wp3, b3, h2f, nullptr, out, nullptr, N);
}